// Round 1
// baseline (79.763 us; speedup 1.0000x reference)
//
#include <hip/hip_runtime.h>
#include <hip/hip_bf16.h>

// QLinear: y[n,o] = round((sum_k (x[n,k]-xz)*(w[o,k]-wz) + bias[o]) * M + yz)
// N=65536, K=512, OUT=512. Exact in bf16-MFMA (|vals|<=128, dots < 2^24).

#define K_DIM 512
#define OUTF  512
#define BM    128
#define BN    128
#define BK    64
#define NT    8          // K_DIM / BK
#define LDA   72         // padded row stride (bf16 elems): 64 + 8 -> 144B, conflict-free
#define AB_ELE (128 * LDA)   // 9216 elems per tile buffer

typedef __attribute__((ext_vector_type(8))) short bf16x8;
typedef __attribute__((ext_vector_type(4))) float f32x4;
typedef __attribute__((ext_vector_type(4))) unsigned short u16x4;
typedef __attribute__((ext_vector_type(4))) unsigned int u32x4;
typedef __attribute__((ext_vector_type(4))) int i32x4;

__device__ __forceinline__ unsigned short f2bf(float f) {
    union { float f; unsigned int u; } v; v.f = f;
    unsigned int u = v.u + 0x7fffu + ((v.u >> 16) & 1u);   // RNE
    return (unsigned short)(u >> 16);
}

// weight int32 [512*512] -> bf16 bits (w - w_zero) in workspace
__global__ void wprep_kernel(const int* __restrict__ W,
                             unsigned short* __restrict__ Wb,
                             const float* __restrict__ wzp) {
    float wz = wzp[0];
    int idx = (blockIdx.x * blockDim.x + threadIdx.x) * 4;
    i32x4 w = *reinterpret_cast<const i32x4*>(W + idx);
    u16x4 h;
    h[0] = f2bf((float)w[0] - wz);
    h[1] = f2bf((float)w[1] - wz);
    h[2] = f2bf((float)w[2] - wz);
    h[3] = f2bf((float)w[3] - wz);
    *reinterpret_cast<u16x4*>(Wb + idx) = h;
}

__global__ __launch_bounds__(256, 2)
void qlinear_gemm(const float* __restrict__ X,
                  const unsigned short* __restrict__ Wb,
                  const int* __restrict__ bias,
                  const float* __restrict__ Mp,
                  const float* __restrict__ xzp,
                  const float* __restrict__ yzp,
                  float* __restrict__ Y) {
    // LDS: A[2][128][72] then B[2][128][72], bf16 bits. 73728 B total.
    __shared__ unsigned short lds[4 * AB_ELE];
    const int BOF = 2 * AB_ELE;

    const int tid = threadIdx.x;
    const int lane = tid & 63;
    const int wid = tid >> 6;
    const int wr = wid >> 1, wc = wid & 1;      // 2x2 wave grid, wave tile 64x64
    const int fr = lane & 15, fq = lane >> 4;

    // XCD-contiguous swizzle: 2048 blocks, 8 XCDs, col-tile fastest within XCD
    const int b = blockIdx.x;
    const int lid = (b & 7) * 256 + (b >> 3);
    const int rowTile = lid >> 2, colTile = lid & 3;
    const int row0 = rowTile * BM;
    const int n0 = colTile * BN;

    const float xz = xzp[0];

    // staging maps (256 threads):
    // A tile 128x64 f32: thread -> col4=(tid&15)*4, rows tid>>4 + i*16 (i=0..7)
    // B tile 128x64 bf16: thread -> col8=(tid&7)*8, rows tid>>3 + i*32 (i=0..3)
    const float* xbase = X + (size_t)(row0 + (tid >> 4)) * K_DIM + (tid & 15) * 4;
    const unsigned short* wbase = Wb + (size_t)(n0 + (tid >> 3)) * K_DIM + (tid & 7) * 8;
    const int awoff = (tid >> 4) * LDA + (tid & 15) * 4;
    const int bwoff = BOF + (tid >> 3) * LDA + (tid & 7) * 8;

    f32x4 ra[8];
    u32x4 rb[4];

    auto loadTile = [&](int t) {
        const float* xp = xbase + t * BK;
        #pragma unroll
        for (int i = 0; i < 8; ++i)
            ra[i] = *reinterpret_cast<const f32x4*>(xp + (size_t)i * 16 * K_DIM);
        const unsigned short* wp = wbase + t * BK;
        #pragma unroll
        for (int i = 0; i < 4; ++i)
            rb[i] = *reinterpret_cast<const u32x4*>(wp + (size_t)i * 32 * K_DIM);
    };
    auto writeTile = [&](int buf) {
        const int ab = buf * AB_ELE;
        #pragma unroll
        for (int i = 0; i < 8; ++i) {
            u16x4 h;
            h[0] = f2bf(ra[i][0] - xz);
            h[1] = f2bf(ra[i][1] - xz);
            h[2] = f2bf(ra[i][2] - xz);
            h[3] = f2bf(ra[i][3] - xz);
            *reinterpret_cast<u16x4*>(&lds[ab + awoff + i * 16 * LDA]) = h;
        }
        #pragma unroll
        for (int i = 0; i < 4; ++i)
            *reinterpret_cast<u32x4*>(&lds[ab + bwoff + i * 32 * LDA]) = rb[i];
    };

    f32x4 acc[4][4] = {};

    // fragment LDS bases (elements)
    const int aro = (wr * 64 + fr) * LDA + fq * 8;
    const int bro = BOF + (wc * 64 + fr) * LDA + fq * 8;

    auto computeTile = [&](int buf) {
        const int ab = buf * AB_ELE;
        #pragma unroll
        for (int ks = 0; ks < 2; ++ks) {
            bf16x8 af[4], bfr[4];
            #pragma unroll
            for (int m = 0; m < 4; ++m)
                af[m] = *reinterpret_cast<const bf16x8*>(&lds[ab + aro + m * 16 * LDA + ks * 32]);
            #pragma unroll
            for (int n = 0; n < 4; ++n)
                bfr[n] = *reinterpret_cast<const bf16x8*>(&lds[ab + bro + n * 16 * LDA + ks * 32]);
            #pragma unroll
            for (int m = 0; m < 4; ++m)
                #pragma unroll
                for (int n = 0; n < 4; ++n)
                    acc[m][n] = __builtin_amdgcn_mfma_f32_16x16x32_bf16(
                        af[m], bfr[n], acc[m][n], 0, 0, 0);
        }
    };

    loadTile(0);
    writeTile(0);
    __syncthreads();

    #pragma unroll
    for (int t = 0; t < NT; ++t) {
        if (t < NT - 1) loadTile(t + 1);      // issue next-tile loads early (T14)
        computeTile(t & 1);
        if (t < NT - 1) writeTile((t + 1) & 1);
        __syncthreads();
    }

    // epilogue
    const float M = Mp[0], yz = yzp[0];
    #pragma unroll
    for (int n = 0; n < 4; ++n) {
        const int col = n0 + wc * 64 + n * 16 + fr;
        const float bv = (float)bias[col];
        #pragma unroll
        for (int m = 0; m < 4; ++m) {
            const int row = row0 + wr * 64 + m * 16 + fq * 4;
            float* yp = Y + (size_t)row * OUTF + col;
            #pragma unroll
            for (int j = 0; j < 4; ++j)
                yp[(size_t)j * OUTF] = rintf((acc[m][n][j] + bv) * M + yz);
        }
    }
}

extern "C" void kernel_launch(void* const* d_in, const int* in_sizes, int n_in,
                              void* d_out, int out_size, void* d_ws, size_t ws_size,
                              hipStream_t stream) {
    const float* x    = (const float*)d_in[0];
    const int*   w    = (const int*)d_in[1];
    const int*   bias = (const int*)d_in[2];
    const float* M    = (const float*)d_in[3];
    const float* xz   = (const float*)d_in[4];
    const float* wz   = (const float*)d_in[5];
    const float* yz   = (const float*)d_in[6];
    float* y = (float*)d_out;
    unsigned short* Wb = (unsigned short*)d_ws;   // 512*512 bf16 = 512 KB

    wprep_kernel<<<256, 256, 0, stream>>>(w, Wb, wz);
    qlinear_gemm<<<2048, 256, 0, stream>>>(x, Wb, bias, M, xz, yz, y);
}

// Round 2
// 76.540 us; speedup vs baseline: 1.0421x; 1.0421x over previous
//
#include <hip/hip_runtime.h>

// QLinear: y[n,o] = round((sum_k (x[n,k]-xz)*(w[o,k]-wz) + bias[o]) * M + yz)
// N=65536, K=512, OUT=512.  Exact in i8 MFMA: (x-128),(w-128) in [-128,127],
// |dot| <= 512*128*128 = 8.4M < 2^24, i32 accum exact, f32 epilogue exact.

#define K_DIM 512
#define OUTF  512
#define BM    128
#define BN    128
#define BK    64
#define NT    8            // K_DIM / BK
#define LDAB  80           // LDS row stride bytes: 64 data + 16 pad (2-way max on b128)
#define TILE_B (128 * LDAB)   // 10240 B per tile
#define BUF_B  (2 * TILE_B)   // A+B per buffer

typedef __attribute__((ext_vector_type(4))) int i32x4;
typedef __attribute__((ext_vector_type(4))) float f32x4;

__device__ __forceinline__ unsigned int pack4(float a, float b, float c, float d, float z) {
    unsigned int b0 = (unsigned int)((int)(a - z)) & 0xffu;
    unsigned int b1 = (unsigned int)((int)(b - z)) & 0xffu;
    unsigned int b2 = (unsigned int)((int)(c - z)) & 0xffu;
    unsigned int b3 = (unsigned int)((int)(d - z)) & 0xffu;
    return b0 | (b1 << 8) | (b2 << 16) | (b3 << 24);
}

// weight int32 [512*512] -> int8 (w - w_zero), row-major [o][k]
__global__ void wprep(const int* __restrict__ W, unsigned int* __restrict__ Wb,
                      const float* __restrict__ wzp) {
    float wz = wzp[0];
    int idx = (blockIdx.x * blockDim.x + threadIdx.x) * 4;
    i32x4 w = *reinterpret_cast<const i32x4*>(W + idx);
    Wb[idx >> 2] = pack4((float)w[0], (float)w[1], (float)w[2], (float)w[3], wz);
}

__global__ __launch_bounds__(512, 4)
void qgemm(const float* __restrict__ X,
           const unsigned char* __restrict__ Wb,
           const int* __restrict__ bias,
           const float* __restrict__ Mp,
           const float* __restrict__ xzp,
           const float* __restrict__ yzp,
           float* __restrict__ Y) {
    __shared__ unsigned char lds[2 * BUF_B];   // 40960 B

    const int tid  = threadIdx.x;
    const int lane = tid & 63;
    const int wid  = tid >> 6;                 // 0..7
    const int wr   = wid >> 2;                 // 0..1  (row 64-strip)
    const int wc   = wid & 3;                  // 0..3  (col 32-strip)
    const int fr   = lane & 15;
    const int fq   = lane >> 4;

    // XCD-contiguous bijective swizzle (2048 = 8 * 256)
    const int b = blockIdx.x;
    const int lid = (b & 7) * 256 + (b >> 3);
    const int row0 = (lid >> 2) * BM;
    const int n0   = (lid & 3) * BN;

    const float xz = xzp[0];

    // staging: 512 threads. A tile 128x64 f32 (32KB): row=tid>>2, 16 f32 at col (tid&3)*16
    //          B tile 128x64 i8 (8KB):   row=tid>>2, 16 B   at col (tid&3)*16
    const int srow = tid >> 2;
    const int scol = (tid & 3) * 16;
    const float* xbase = X + (size_t)(row0 + srow) * K_DIM + scol;
    const unsigned char* wbase = Wb + (size_t)(n0 + srow) * K_DIM + scol;
    const int aoff = srow * LDAB + scol;          // bytes (i8 dest)
    const int boff = TILE_B + srow * LDAB + scol;

    f32x4 ra[4];
    i32x4 rb;

    auto stage = [&](int t) {
        const float* xp = xbase + t * BK;
        #pragma unroll
        for (int q = 0; q < 4; ++q)
            ra[q] = *reinterpret_cast<const f32x4*>(xp + q * 4);
        rb = *reinterpret_cast<const i32x4*>(wbase + t * BK);
    };
    auto convwrite = [&](int buf) {
        const int ab = buf * BUF_B;
        i32x4 pa;
        #pragma unroll
        for (int q = 0; q < 4; ++q)
            pa[q] = (int)pack4(ra[q][0], ra[q][1], ra[q][2], ra[q][3], xz);
        *reinterpret_cast<i32x4*>(&lds[ab + aoff]) = pa;
        *reinterpret_cast<i32x4*>(&lds[ab + boff]) = rb;
    };

    i32x4 acc[4][2] = {};

    const int aro = (wr * 64 + fr) * LDAB + fq * 16;
    const int bro = TILE_B + (wc * 32 + fr) * LDAB + fq * 16;

    auto compute = [&](int buf) {
        const int ab = buf * BUF_B;
        i32x4 af[4], bf[2];
        #pragma unroll
        for (int m = 0; m < 4; ++m)
            af[m] = *reinterpret_cast<const i32x4*>(&lds[ab + aro + m * 16 * LDAB]);
        #pragma unroll
        for (int n = 0; n < 2; ++n)
            bf[n] = *reinterpret_cast<const i32x4*>(&lds[ab + bro + n * 16 * LDAB]);
        #pragma unroll
        for (int m = 0; m < 4; ++m)
            #pragma unroll
            for (int n = 0; n < 2; ++n)
                acc[m][n] = __builtin_amdgcn_mfma_i32_16x16x64_i8(
                    af[m], bf[n], acc[m][n], 0, 0, 0);
    };

    stage(0);
    convwrite(0);
    __syncthreads();

    #pragma unroll
    for (int t = 0; t < NT; ++t) {
        if (t < NT - 1) stage(t + 1);        // issue next-tile loads early (T14)
        compute(t & 1);
        if (t < NT - 1) convwrite((t + 1) & 1);
        __syncthreads();
    }

    // epilogue: y = rintf((acc + bias) * M + yz)
    const float M = Mp[0], yz = yzp[0];
    #pragma unroll
    for (int n = 0; n < 2; ++n) {
        const int col = n0 + wc * 32 + n * 16 + fr;
        const int bv = bias[col];
        #pragma unroll
        for (int m = 0; m < 4; ++m) {
            const int row = row0 + wr * 64 + m * 16 + fq * 4;
            float* yp = Y + (size_t)row * OUTF + col;
            #pragma unroll
            for (int j = 0; j < 4; ++j)
                yp[(size_t)j * OUTF] = rintf((float)(acc[m][n][j] + bv) * M + yz);
        }
    }
}

extern "C" void kernel_launch(void* const* d_in, const int* in_sizes, int n_in,
                              void* d_out, int out_size, void* d_ws, size_t ws_size,
                              hipStream_t stream) {
    const float* x    = (const float*)d_in[0];
    const int*   w    = (const int*)d_in[1];
    const int*   bias = (const int*)d_in[2];
    const float* M    = (const float*)d_in[3];
    const float* xz   = (const float*)d_in[4];
    const float* wz   = (const float*)d_in[5];
    const float* yz   = (const float*)d_in[6];
    float* y = (float*)d_out;
    unsigned int* Wb = (unsigned int*)d_ws;   // 512*512 i8 = 256 KB

    wprep<<<256, 256, 0, stream>>>(w, Wb, wz);
    qgemm<<<2048, 512, 0, stream>>>(x, (const unsigned char*)Wb, bias, M, xz, yz, y);
}